// Round 1
// baseline (324.482 us; speedup 1.0000x reference)
//
#include <hip/hip_runtime.h>
#include <stdint.h>

typedef unsigned int u32;
typedef unsigned long long u64;

#define SCORE_THR 0.05f
#define NMS_THR   0.5f
#define TK        2048
#define CAP       4096
#define HIST_BASE 0x3D00u

// ---------------- ws layout (bytes) ----------------
// 0       : hist1   u32[1024]           (zeroed per call)
// 4096    : hist2   u32[1024]           (zeroed per call)
// 8192    : hdr     u32[16]             (zeroed per call)
//           hdr[0]=takeall hdr[1]=B1abs hdr[2]=cgt1 hdr[3]=thr26 hdr[4]=collect count
// 16384   : buf     u64[4096]   (32 KB)
// 49152   : cand_bx f32[2048*4] (32 KB)
// 81920   : nms_bx  f32[2048*4] (32 KB)
// 114688  : vals    f32[2048]   ( 8 KB)
// 122880  : mask    u32[2048*64](512 KB)   -> total 647168 B
#define WS_HIST1 0
#define WS_HIST2 4096
#define WS_HDR   8192
#define WS_BUF   16384
#define WS_CBX   49152
#define WS_NBX   81920
#define WS_VALS  114688
#define WS_MASK  122880

// ---- histogram pass (level 0: top16 bits; level 1: bits[15:6] within bin B1) ----
__global__ void k_hist(const float* __restrict__ scores,
                       const float* __restrict__ center,
                       int R, u32* __restrict__ hist,
                       const u32* __restrict__ hdr, int level) {
    __shared__ u32 h[1024];
    for (int t = threadIdx.x; t < 1024; t += blockDim.x) h[t] = 0;
    __syncthreads();
    u32 b1abs = 0;
    if (level == 1) {
        if (hdr[0] == 1) return;   // takeall: no refinement needed
        b1abs = hdr[1];
    }
    int stride = gridDim.x * blockDim.x;
    for (int r = blockIdx.x * blockDim.x + threadIdx.x; r < R; r += stride) {
        float cs = center[r];
        const float* srow = scores + (size_t)r * 11 + 1;
#pragma unroll
        for (int k = 0; k < 10; k++) {
            float s = __fmul_rn(srow[k], cs);
            if (s > SCORE_THR) {
                u32 key = __float_as_uint(s);
                if (level == 0) {
                    int b = (int)(key >> 16) - (int)HIST_BASE;
                    b = min(max(b, 0), 1023);
                    atomicAdd(&h[b], 1u);
                } else if ((key >> 16) == b1abs) {
                    atomicAdd(&h[(key >> 6) & 0x3FFu], 1u);
                }
            }
        }
    }
    __syncthreads();
    for (int t = threadIdx.x; t < 1024; t += blockDim.x)
        if (h[t]) atomicAdd(&hist[t], h[t]);
}

// ---- scan: find the bin containing the 2048th element (one wave) ----
__global__ void k_scan(const u32* __restrict__ hist, u32* hdr, int level) {
    int lane = threadIdx.x;  // 64 threads = 1 wave
    if (level == 1 && hdr[0] == 1) { if (lane == 0) hdr[3] = 0; return; }
    u32 target = (level == 0) ? (u32)TK : ((u32)TK - hdr[2]);
    int base = 1024 - 16 * (lane + 1);   // lane 0 = topmost segment
    u32 v[16];
    u32 segsum = 0;
#pragma unroll
    for (int j = 0; j < 16; j++) { v[j] = hist[base + j]; segsum += v[j]; }
    u32 incl = segsum;
    for (int off = 1; off < 64; off <<= 1) {
        u32 t = (u32)__shfl_up((int)incl, off);
        if (lane >= off) incl += t;
    }
    u32 excl = incl - segsum;
    u32 total = (u32)__shfl((int)incl, 63);
    if (level == 0 && total < target) {
        if (lane == 0) { hdr[0] = 1; hdr[1] = 0; hdr[2] = 0; }
        return;
    }
    bool cross = (excl < target) && (incl >= target);
    if (cross) {
        u32 cum = excl;
        int b = base;
        u32 cgt = excl;
#pragma unroll
        for (int j = 15; j >= 0; j--) {
            u32 nc = cum + v[j];
            if (nc >= target) { b = base + j; cgt = cum; break; }
            cum = nc;
        }
        if (level == 0) {
            hdr[0] = 0u;  // already 0 from memset, but harmless
            hdr[1] = HIST_BASE + (u32)b;
            hdr[2] = cgt;
        } else {
            hdr[3] = (hdr[1] << 10) | (u32)b;
        }
    }
}

// ---- collect all candidates at/above the 26-bit pivot ----
__global__ void k_collect(const float* __restrict__ scores,
                          const float* __restrict__ center,
                          int R, u32* __restrict__ hdr, u64* __restrict__ buf) {
    u32 takeall = hdr[0];
    u32 thr26 = hdr[3];
    int stride = gridDim.x * blockDim.x;
    for (int r = blockIdx.x * blockDim.x + threadIdx.x; r < R; r += stride) {
        float cs = center[r];
        const float* srow = scores + (size_t)r * 11 + 1;
#pragma unroll
        for (int k = 0; k < 10; k++) {
            float s = __fmul_rn(srow[k], cs);
            if (s > SCORE_THR) {
                u32 key = __float_as_uint(s);
                if (takeall || (key >> 6) >= thr26) {
                    u32 pos = atomicAdd(&hdr[4], 1u);
                    if (pos < CAP) {
                        u32 idx = (u32)r * 10u + (u32)k;
                        buf[pos] = ((u64)key << 32) | (u64)(~idx);
                    }
                }
            }
        }
    }
}

// ---- sort 4096 (bitonic, LDS) + gather boxes / build NMS boxes ----
__global__ __launch_bounds__(1024) void k_sortgather(
        const float* __restrict__ boxes, const u32* __restrict__ hdr,
        const u64* __restrict__ buf, float* __restrict__ cand_bx,
        float* __restrict__ nms_bx, float* __restrict__ vals) {
    __shared__ u64 a[CAP];
    int tid = threadIdx.x;
    u32 n = hdr[4]; if (n > CAP) n = CAP;
    for (int t = tid; t < CAP; t += 1024) a[t] = (t < (int)n) ? buf[t] : 0ull;
    __syncthreads();
    for (u32 kk = 2; kk <= CAP; kk <<= 1) {
        for (u32 j = kk >> 1; j > 0; j >>= 1) {
            for (int t = tid; t < CAP; t += 1024) {
                int ixj = t ^ (int)j;
                if (ixj > t) {
                    u64 x = a[t], y = a[ixj];
                    bool up = ((t & (int)kk) == 0);
                    if ((x > y) == up) { a[t] = y; a[ixj] = x; }
                }
            }
            __syncthreads();
        }
    }
    // rank t (descending value, ascending idx on ties) = a[CAP-1-t]
    for (int t = tid; t < TK; t += 1024) {
        u64 v = a[CAP - 1 - t];
        u32 key = (u32)(v >> 32);
        float c0 = 0.f, c1 = 0.f, c2 = 0.f, c3 = 0.f;
        float n0 = 0.f, n1 = 0.f, n2 = 0.f, n3 = 0.f;
        float val = -1.0f;
        if (key != 0) {
            u32 idx = ~(u32)v;
            u32 r = idx / 10u, cls = idx % 10u;
            const float* bp = boxes + (size_t)r * 4;
            c0 = fminf(fmaxf(bp[0], 0.f), 1920.f);
            c1 = fminf(fmaxf(bp[1], 0.f), 1080.f);
            c2 = fminf(fmaxf(bp[2], 0.f), 1920.f);
            c3 = fminf(fmaxf(bp[3], 0.f), 1080.f);
            float offv = __fmul_rn((float)cls, 3001.0f);  // exact: small ints
            n0 = __fadd_rn(c0, offv); n1 = __fadd_rn(c1, offv);
            n2 = __fadd_rn(c2, offv); n3 = __fadd_rn(c3, offv);
            val = __uint_as_float(key);
        }
        cand_bx[t * 4 + 0] = c0; cand_bx[t * 4 + 1] = c1;
        cand_bx[t * 4 + 2] = c2; cand_bx[t * 4 + 3] = c3;
        nms_bx[t * 4 + 0] = n0; nms_bx[t * 4 + 1] = n1;
        nms_bx[t * 4 + 2] = n2; nms_bx[t * 4 + 3] = n3;
        vals[t] = val;
    }
}

// ---- suppression bitmask: mask[row][word] over 2048x2048 pairs ----
__global__ void k_mask(const float* __restrict__ nms_bx, u32* __restrict__ mask) {
    __shared__ float4 cb[64];
    __shared__ float ca[64];
    int tid = threadIdx.x;
    int colbase = blockIdx.x * 64, rowbase = blockIdx.y * 64;
    float4 c = ((const float4*)nms_bx)[colbase + tid];
    cb[tid] = c;
    ca[tid] = __fmul_rn(fmaxf(__fsub_rn(c.z, c.x), 0.f),
                        fmaxf(__fsub_rn(c.w, c.y), 0.f));
    int row = rowbase + tid;
    float4 rb = ((const float4*)nms_bx)[row];
    float rarea = __fmul_rn(fmaxf(__fsub_rn(rb.z, rb.x), 0.f),
                            fmaxf(__fsub_rn(rb.w, rb.y), 0.f));
    __syncthreads();
    u32 w0 = 0, w1 = 0;
    for (int cc = 0; cc < 64; cc++) {
        int col = colbase + cc;
        if (col > row) {
            float4 cbv = cb[cc];
            float ltx = fmaxf(rb.x, cbv.x), lty = fmaxf(rb.y, cbv.y);
            float rbx = fminf(rb.z, cbv.z), rby = fminf(rb.w, cbv.w);
            float w = fmaxf(__fsub_rn(rbx, ltx), 0.f);
            float h = fmaxf(__fsub_rn(rby, lty), 0.f);
            float inter = __fmul_rn(w, h);
            // ref order: ((area_i + area_j) - inter) + 1e-9
            float denom = __fadd_rn(__fsub_rn(__fadd_rn(rarea, ca[cc]), inter), 1e-9f);
            float iou = __fdiv_rn(inter, denom);
            if (iou > NMS_THR) {
                if (cc < 32) w0 |= 1u << cc; else w1 |= 1u << (cc - 32);
            }
        }
    }
    mask[row * 64 + blockIdx.x * 2 + 0] = w0;
    mask[row * 64 + blockIdx.x * 2 + 1] = w1;
}

// ---- serial greedy scan (1 wave) + output write ----
__global__ void k_final(const u32* __restrict__ mask, const float* __restrict__ vals,
                        const float* __restrict__ cand_bx, float* __restrict__ out) {
    int lane = threadIdx.x;  // 64 lanes; lane owns removed/keep bits [lane*32, lane*32+32)
    u32 validw = 0;
#pragma unroll
    for (int b = 0; b < 32; b++)
        validw |= (vals[lane * 32 + b] > SCORE_THR ? 1u : 0u) << b;
    u32 removed = 0, keepw = 0;
    for (int chunk = 0; chunk < TK; chunk += 16) {
        u32 rowbuf[16];
#pragma unroll
        for (int j = 0; j < 16; j++)
            rowbuf[j] = mask[(chunk + j) * 64 + lane];
#pragma unroll
        for (int j = 0; j < 16; j++) {
            int i = chunk + j;
            u32 alive = validw & ~removed;
            u32 aw = (u32)__shfl((int)alive, i >> 5);
            u32 keep_i = (aw >> (i & 31)) & 1u;
            removed |= keep_i ? rowbuf[j] : 0u;
            if (lane == (i >> 5)) keepw |= keep_i << (i & 31);
        }
    }
    for (int b = 0; b < 32; b++) {
        int i = lane * 32 + b;
        bool kp = (keepw >> b) & 1u;
        const float4 bx = ((const float4*)cand_bx)[i];
        out[i * 5 + 0] = kp ? bx.x : 0.f;
        out[i * 5 + 1] = kp ? bx.y : 0.f;
        out[i * 5 + 2] = kp ? bx.z : 0.f;
        out[i * 5 + 3] = kp ? bx.w : 0.f;
        out[i * 5 + 4] = kp ? vals[i] : 0.f;
    }
}

extern "C" void kernel_launch(void* const* d_in, const int* in_sizes, int n_in,
                              void* d_out, int out_size, void* d_ws, size_t ws_size,
                              hipStream_t stream) {
    const float* boxes = (const float*)d_in[0];
    const float* scores = (const float*)d_in[1];
    const float* center = (const float*)d_in[2];
    float* out = (float*)d_out;
    int R = in_sizes[2];

    char* w = (char*)d_ws;
    u32* hist1 = (u32*)(w + WS_HIST1);
    u32* hist2 = (u32*)(w + WS_HIST2);
    u32* hdr   = (u32*)(w + WS_HDR);
    u64* buf   = (u64*)(w + WS_BUF);
    float* cbx = (float*)(w + WS_CBX);
    float* nbx = (float*)(w + WS_NBX);
    float* vls = (float*)(w + WS_VALS);
    u32* mask  = (u32*)(w + WS_MASK);

    // ws is poisoned 0xAA before every call: zero the histograms + header
    hipMemsetAsync(w, 0, WS_BUF, stream);

    k_hist<<<1024, 256, 0, stream>>>(scores, center, R, hist1, hdr, 0);
    k_scan<<<1, 64, 0, stream>>>(hist1, hdr, 0);
    k_hist<<<1024, 256, 0, stream>>>(scores, center, R, hist2, hdr, 1);
    k_scan<<<1, 64, 0, stream>>>(hist2, hdr, 1);
    k_collect<<<1024, 256, 0, stream>>>(scores, center, R, hdr, buf);
    k_sortgather<<<1, 1024, 0, stream>>>(boxes, hdr, buf, cbx, nbx, vls);
    k_mask<<<dim3(32, 32), 64, 0, stream>>>(nbx, mask);
    k_final<<<1, 64, 0, stream>>>(mask, vls, cbx, out);
}

// Round 2
// 252.450 us; speedup vs baseline: 1.2853x; 1.2853x over previous
//
#include <hip/hip_runtime.h>
#include <stdint.h>

typedef unsigned int u32;
typedef unsigned long long u64;

#define SCORE_THR 0.05f
#define NMS_THR   0.5f
#define TK        2048
#define CAP       4096
#define BASE14    (0x3D4CCCCDu >> 14)   // (bits of 0.05f) >> 14

// ---------------- ws layout (bytes) ----------------
// 0      : hist  u32[4096]  (zeroed per call)
// 16384  : hdr   u32[16]    (zeroed per call)  hdr[0]=takeall hdr[3]=thr14 hdr[4]=count
// 16448  : buf   u64[4096]  (32 KB)
// 49216  : cand_bx f32[2048*4]
// 81984  : nms_bx  f32[2048*4]
// 114752 : vals    f32[2048]
// 122944 : mask    u32[2048*64] (512 KB)  -> total 647232 B
#define WS_HIST 0
#define WS_HDR  16384
#define WS_BUF  16448
#define WS_CBX  49216
#define WS_NBX  81984
#define WS_VALS 114752
#define WS_MASK 122944

// ---- single-pass histogram over key bits [30:14] (4096 bins) ----
__global__ void k_hist(const float* __restrict__ scores,
                       const float* __restrict__ center,
                       int R, u32* __restrict__ hist) {
    __shared__ u32 h[4096];
    for (int t = threadIdx.x; t < 4096; t += blockDim.x) h[t] = 0;
    __syncthreads();
    int stride = gridDim.x * blockDim.x;
    for (int r = blockIdx.x * blockDim.x + threadIdx.x; r < R; r += stride) {
        float cs = center[r];
        const float* srow = scores + (size_t)r * 11 + 1;
#pragma unroll
        for (int k = 0; k < 10; k++) {
            float s = __fmul_rn(srow[k], cs);
            if (s > SCORE_THR) {
                u32 key = __float_as_uint(s);
                int b = (int)(key >> 14) - (int)BASE14;
                b = min(max(b, 0), 4095);
                atomicAdd(&h[b], 1u);
            }
        }
    }
    __syncthreads();
    for (int t = threadIdx.x; t < 4096; t += blockDim.x)
        if (h[t]) atomicAdd(&hist[t], h[t]);
}

// ---- scan: find pivot bin containing the 2048th element (one wave) ----
__global__ void k_scan(const u32* __restrict__ hist, u32* hdr) {
    int lane = threadIdx.x;             // 64 lanes x 64 bins
    int base = 4096 - 64 * (lane + 1);  // lane 0 = topmost segment
    u32 v[64];
    u32 segsum = 0;
#pragma unroll
    for (int j = 0; j < 64; j++) { v[j] = hist[base + j]; segsum += v[j]; }
    u32 incl = segsum;
    for (int off = 1; off < 64; off <<= 1) {
        u32 t = (u32)__shfl_up((int)incl, off);
        if (lane >= off) incl += t;
    }
    u32 excl = incl - segsum;
    u32 total = (u32)__shfl((int)incl, 63);
    if (total < (u32)TK) {
        if (lane == 0) { hdr[0] = 1; hdr[3] = 0; }
        return;
    }
    bool cross = (excl < (u32)TK) && (incl >= (u32)TK);
    if (cross) {
        u32 cum = excl;
#pragma unroll
        for (int j = 63; j >= 0; j--) {
            u32 nc = cum + v[j];
            if (nc >= (u32)TK) { hdr[3] = BASE14 + (u32)(base + j); break; }
            cum = nc;
        }
    }
}

// ---- collect all candidates at/above the pivot bin ----
__global__ void k_collect(const float* __restrict__ scores,
                          const float* __restrict__ center,
                          int R, u32* __restrict__ hdr, u64* __restrict__ buf) {
    u32 takeall = hdr[0];
    u32 thr14 = hdr[3];
    int stride = gridDim.x * blockDim.x;
    for (int r = blockIdx.x * blockDim.x + threadIdx.x; r < R; r += stride) {
        float cs = center[r];
        const float* srow = scores + (size_t)r * 11 + 1;
#pragma unroll
        for (int k = 0; k < 10; k++) {
            float s = __fmul_rn(srow[k], cs);
            if (s > SCORE_THR) {
                u32 key = __float_as_uint(s);
                if (takeall || (key >> 14) >= thr14) {
                    u32 pos = atomicAdd(&hdr[4], 1u);
                    if (pos < CAP) {
                        u32 idx = (u32)r * 10u + (u32)k;
                        buf[pos] = ((u64)key << 32) | (u64)(~idx);
                    }
                }
            }
        }
    }
}

// ---- sort 4096 (bitonic, LDS) + gather boxes / build NMS boxes ----
__global__ __launch_bounds__(1024) void k_sortgather(
        const float* __restrict__ boxes, const u32* __restrict__ hdr,
        const u64* __restrict__ buf, float* __restrict__ cand_bx,
        float* __restrict__ nms_bx, float* __restrict__ vals) {
    __shared__ u64 a[CAP];
    int tid = threadIdx.x;
    u32 n = hdr[4]; if (n > CAP) n = CAP;
    for (int t = tid; t < CAP; t += 1024) a[t] = (t < (int)n) ? buf[t] : 0ull;
    __syncthreads();
    for (u32 kk = 2; kk <= CAP; kk <<= 1) {
        for (u32 j = kk >> 1; j > 0; j >>= 1) {
            for (int t = tid; t < CAP; t += 1024) {
                int ixj = t ^ (int)j;
                if (ixj > t) {
                    u64 x = a[t], y = a[ixj];
                    bool up = ((t & (int)kk) == 0);
                    if ((x > y) == up) { a[t] = y; a[ixj] = x; }
                }
            }
            __syncthreads();
        }
    }
    // rank t (descending value, ascending idx on ties) = a[CAP-1-t]
    for (int t = tid; t < TK; t += 1024) {
        u64 v = a[CAP - 1 - t];
        u32 key = (u32)(v >> 32);
        float c0 = 0.f, c1 = 0.f, c2 = 0.f, c3 = 0.f;
        float n0 = 0.f, n1 = 0.f, n2 = 0.f, n3 = 0.f;
        float val = -1.0f;
        if (key != 0) {
            u32 idx = ~(u32)v;
            u32 r = idx / 10u, cls = idx % 10u;
            const float* bp = boxes + (size_t)r * 4;
            c0 = fminf(fmaxf(bp[0], 0.f), 1920.f);
            c1 = fminf(fmaxf(bp[1], 0.f), 1080.f);
            c2 = fminf(fmaxf(bp[2], 0.f), 1920.f);
            c3 = fminf(fmaxf(bp[3], 0.f), 1080.f);
            float offv = __fmul_rn((float)cls, 3001.0f);  // exact: small ints
            n0 = __fadd_rn(c0, offv); n1 = __fadd_rn(c1, offv);
            n2 = __fadd_rn(c2, offv); n3 = __fadd_rn(c3, offv);
            val = __uint_as_float(key);
        }
        cand_bx[t * 4 + 0] = c0; cand_bx[t * 4 + 1] = c1;
        cand_bx[t * 4 + 2] = c2; cand_bx[t * 4 + 3] = c3;
        nms_bx[t * 4 + 0] = n0; nms_bx[t * 4 + 1] = n1;
        nms_bx[t * 4 + 2] = n2; nms_bx[t * 4 + 3] = n3;
        vals[t] = val;
    }
}

// ---- suppression bitmask: mask[row][word] over 2048x2048 pairs ----
__global__ void k_mask(const float* __restrict__ nms_bx, u32* __restrict__ mask) {
    __shared__ float4 cb[64];
    __shared__ float ca[64];
    int tid = threadIdx.x;
    int colbase = blockIdx.x * 64, rowbase = blockIdx.y * 64;
    float4 c = ((const float4*)nms_bx)[colbase + tid];
    cb[tid] = c;
    ca[tid] = __fmul_rn(fmaxf(__fsub_rn(c.z, c.x), 0.f),
                        fmaxf(__fsub_rn(c.w, c.y), 0.f));
    int row = rowbase + tid;
    float4 rb = ((const float4*)nms_bx)[row];
    float rarea = __fmul_rn(fmaxf(__fsub_rn(rb.z, rb.x), 0.f),
                            fmaxf(__fsub_rn(rb.w, rb.y), 0.f));
    __syncthreads();
    u32 w0 = 0, w1 = 0;
    for (int cc = 0; cc < 64; cc++) {
        int col = colbase + cc;
        if (col > row) {
            float4 cbv = cb[cc];
            float ltx = fmaxf(rb.x, cbv.x), lty = fmaxf(rb.y, cbv.y);
            float rbx = fminf(rb.z, cbv.z), rby = fminf(rb.w, cbv.w);
            float w = fmaxf(__fsub_rn(rbx, ltx), 0.f);
            float h = fmaxf(__fsub_rn(rby, lty), 0.f);
            float inter = __fmul_rn(w, h);
            // ref order: ((area_i + area_j) - inter) + 1e-9
            float denom = __fadd_rn(__fsub_rn(__fadd_rn(rarea, ca[cc]), inter), 1e-9f);
            float iou = __fdiv_rn(inter, denom);
            if (iou > NMS_THR) {
                if (cc < 32) w0 |= 1u << cc; else w1 |= 1u << (cc - 32);
            }
        }
    }
    mask[row * 64 + blockIdx.x * 2 + 0] = w0;
    mask[row * 64 + blockIdx.x * 2 + 1] = w1;
}

// ---- greedy scan: word-parallel (64 broadcasts total, not 2048) ----
__global__ void k_final(const u32* __restrict__ mask, const float* __restrict__ vals,
                        const float* __restrict__ cand_bx, float* __restrict__ out) {
    int lane = threadIdx.x;  // lane owns keep/removed bits [lane*32, lane*32+32)
    u32 validw = 0;
#pragma unroll
    for (int b = 0; b < 32; b++)
        validw |= (vals[lane * 32 + b] > SCORE_THR ? 1u : 0u) << b;
    u32 removed = 0, keepw = 0;
    u32 bufA[32], bufB[32];
#pragma unroll
    for (int j = 0; j < 32; j++) bufA[j] = mask[j * 64 + lane];
    for (int w = 0; w < 64; w += 2) {
        // prefetch rows for word w+1
#pragma unroll
        for (int j = 0; j < 32; j++) bufB[j] = mask[((w + 1) * 32 + j) * 64 + lane];
        // ---- resolve word w (lane w's bufA is the intra-word suppression) ----
        {
            u32 alive = validw & ~removed;
#pragma unroll
            for (int j = 0; j < 32; j++)
                alive &= ((alive >> j) & 1u) ? ~bufA[j] : 0xFFFFFFFFu;
            u32 kw = (u32)__shfl((int)alive, w);
            if (lane == w) keepw = kw;
            u32 acc = 0;
#pragma unroll
            for (int j = 0; j < 32; j++) acc |= ((kw >> j) & 1u) ? bufA[j] : 0u;
            removed |= acc;
        }
        // prefetch rows for word w+2
        if (w + 2 < 64) {
#pragma unroll
            for (int j = 0; j < 32; j++) bufA[j] = mask[((w + 2) * 32 + j) * 64 + lane];
        }
        // ---- resolve word w+1 with bufB ----
        {
            u32 alive = validw & ~removed;
#pragma unroll
            for (int j = 0; j < 32; j++)
                alive &= ((alive >> j) & 1u) ? ~bufB[j] : 0xFFFFFFFFu;
            u32 kw = (u32)__shfl((int)alive, w + 1);
            if (lane == w + 1) keepw = kw;
            u32 acc = 0;
#pragma unroll
            for (int j = 0; j < 32; j++) acc |= ((kw >> j) & 1u) ? bufB[j] : 0u;
            removed |= acc;
        }
    }
#pragma unroll
    for (int b = 0; b < 32; b++) {
        int i = lane * 32 + b;
        bool kp = (keepw >> b) & 1u;
        const float4 bx = ((const float4*)cand_bx)[i];
        out[i * 5 + 0] = kp ? bx.x : 0.f;
        out[i * 5 + 1] = kp ? bx.y : 0.f;
        out[i * 5 + 2] = kp ? bx.z : 0.f;
        out[i * 5 + 3] = kp ? bx.w : 0.f;
        out[i * 5 + 4] = kp ? vals[i] : 0.f;
    }
}

extern "C" void kernel_launch(void* const* d_in, const int* in_sizes, int n_in,
                              void* d_out, int out_size, void* d_ws, size_t ws_size,
                              hipStream_t stream) {
    const float* boxes = (const float*)d_in[0];
    const float* scores = (const float*)d_in[1];
    const float* center = (const float*)d_in[2];
    float* out = (float*)d_out;
    int R = in_sizes[2];

    char* w = (char*)d_ws;
    u32* hist = (u32*)(w + WS_HIST);
    u32* hdr  = (u32*)(w + WS_HDR);
    u64* buf  = (u64*)(w + WS_BUF);
    float* cbx = (float*)(w + WS_CBX);
    float* nbx = (float*)(w + WS_NBX);
    float* vls = (float*)(w + WS_VALS);
    u32* mask  = (u32*)(w + WS_MASK);

    // ws is poisoned 0xAA before every call: zero histogram + header
    hipMemsetAsync(w, 0, WS_BUF, stream);

    k_hist<<<1024, 256, 0, stream>>>(scores, center, R, hist);
    k_scan<<<1, 64, 0, stream>>>(hist, hdr);
    k_collect<<<1024, 256, 0, stream>>>(scores, center, R, hdr, buf);
    k_sortgather<<<1, 1024, 0, stream>>>(boxes, hdr, buf, cbx, nbx, vls);
    k_mask<<<dim3(32, 32), 64, 0, stream>>>(nbx, mask);
    k_final<<<1, 64, 0, stream>>>(mask, vls, cbx, out);
}